// Round 3
// baseline (501.927 us; speedup 1.0000x reference)
//
#include <hip/hip_runtime.h>

#define NC 21
#define NB 8
#define HW (512*512)
#define EPS 1e-8f
#define CM_N (NC * NC)   // 441

// Phase 1: per-block private confusion tile. Each block: tilesPerBlock tiles of
// 1024 pixels (256 threads x float4). Argmax with all-21 planes preloaded into
// registers (MLP), target scatter via LDS ds_add, then NON-ATOMIC flush to a
// private partial slot. (Round-2 lesson: 903k contended cross-XCD global
// atomics into 14 KB was the bottleneck -> 1.29 TB/s effective.)
__global__ __launch_bounds__(256) void cm_accum(const float* __restrict__ input,
                                                const float* __restrict__ target,
                                                float* __restrict__ partial,
                                                int tilesPerBlock) {
    __shared__ float scm[CM_N];
    const int t = threadIdx.x;
    for (int i = t; i < CM_N; i += 256) scm[i] = 0.0f;
    __syncthreads();

    const int tilesPerBatch  = 256;                      // 256 tiles x 1024 px = HW
    const int blocksPerBatch = tilesPerBatch / tilesPerBlock;
    const int b     = blockIdx.x / blocksPerBatch;
    const int tile0 = (blockIdx.x % blocksPerBatch) * tilesPerBlock;

    const float4* ip = (const float4*)(input  + (size_t)b * NC * HW);
    const float4* tp = (const float4*)(target + (size_t)b * NC * HW);
    const int plane4 = HW / 4;

    for (int tt = 0; tt < tilesPerBlock; ++tt) {
        const int q = (tile0 + tt) * 256 + t;

        // preload all 21 channel values -> 21 loads in flight (MLP)
        float4 v[NC];
        #pragma unroll
        for (int c = 0; c < NC; ++c) v[c] = ip[c * plane4 + q];

        float4 m = v[0];
        int jx = 0, jy = 0, jz = 0, jw = 0;
        #pragma unroll
        for (int c = 1; c < NC; ++c) {
            if (v[c].x > m.x) { m.x = v[c].x; jx = c; }
            if (v[c].y > m.y) { m.y = v[c].y; jy = c; }
            if (v[c].z > m.z) { m.z = v[c].z; jz = c; }
            if (v[c].w > m.w) { m.w = v[c].w; jw = c; }
        }

        // target scatter, prefetched in chunks of 7 (21 = 3*7)
        #pragma unroll
        for (int i0 = 0; i0 < NC; i0 += 7) {
            float4 y[7];
            #pragma unroll
            for (int k = 0; k < 7; ++k) y[k] = tp[(i0 + k) * plane4 + q];
            #pragma unroll
            for (int k = 0; k < 7; ++k) {
                const int row = (i0 + k) * NC;
                atomicAdd(&scm[row + jx], y[k].x);
                atomicAdd(&scm[row + jy], y[k].y);
                atomicAdd(&scm[row + jz], y[k].z);
                atomicAdd(&scm[row + jw], y[k].w);
            }
        }
    }
    __syncthreads();

    // non-atomic private flush: block-exclusive contiguous 441-float slot
    float* dst = partial + (size_t)blockIdx.x * CM_N;
    for (int i = t; i < CM_N; i += 256) dst[i] = scm[i];
}

// Phase 2: tree-reduce partials into per-batch cm. Grid = NB * segs blocks;
// each block sums blocksPerBatch/segs partial slots (coalesced: thread t owns
// entries t and t+256), then ONE atomic per entry per block (segs=8 adds per
// address total -> negligible contention).
__global__ __launch_bounds__(256) void cm_reduce(const float* __restrict__ partial,
                                                 float* __restrict__ cm,
                                                 int blocksPerBatch, int segs) {
    const int b   = blockIdx.x / segs;
    const int s   = blockIdx.x % segs;
    const int per = blocksPerBatch / segs;
    const float* base = partial + ((size_t)b * blocksPerBatch + (size_t)s * per) * CM_N;
    const int t = threadIdx.x;
    float a0 = 0.0f, a1 = 0.0f;
    for (int k = 0; k < per; ++k) {
        const float* p = base + (size_t)k * CM_N;
        a0 += p[t];
        if (t < CM_N - 256) a1 += p[256 + t];
    }
    atomicAdd(&cm[b * CM_N + t], a0);
    if (t < CM_N - 256) atomicAdd(&cm[b * CM_N + 256 + t], a1);
}

// Phase 3: rowsum[b,i] = sum_j cm[b,i,j] (exact: one-hot sums to 1 per pixel),
// out[i,j] = mean_b cm[b,i,j] / (rowsum[b,i] + EPS)
__global__ __launch_bounds__(512) void cm_final(const float* __restrict__ cm,
                                                float* __restrict__ out) {
    __shared__ float rs[NB * NC];
    const int t = threadIdx.x;
    if (t < NB * NC) {
        const int b = t / NC, i = t % NC;
        float s = 0.0f;
        for (int j = 0; j < NC; ++j) s += cm[b * CM_N + i * NC + j];
        rs[t] = s + EPS;
    }
    __syncthreads();
    if (t < CM_N) {
        const int i = t / NC;
        float acc = 0.0f;
        for (int b = 0; b < NB; ++b) acc += cm[b * CM_N + t] / rs[b * NC + i];
        out[t] = acc * (1.0f / NB);
    }
}

extern "C" void kernel_launch(void* const* d_in, const int* in_sizes, int n_in,
                              void* d_out, int out_size, void* d_ws, size_t ws_size,
                              hipStream_t stream) {
    const float* input  = (const float*)d_in[0];
    const float* target = (const float*)d_in[1];
    float* out = (float*)d_out;

    // ws layout: cm[NB*441] | partial[numBlocks*441]
    float* cm      = (float*)d_ws;
    float* partial = cm + NB * CM_N;

    // prefer 2048 blocks (T=1, 3.6 MB partials); fall back to 256 blocks (T=8)
    int T = 1;
    size_t need = ((size_t)NB * 256 / T * CM_N + NB * CM_N) * sizeof(float);
    if (ws_size < need) T = 8;
    const int blocksPerBatch = 256 / T;
    const int numBlocks = NB * blocksPerBatch;
    const int segs = blocksPerBatch >= 8 ? 8 : 1;

    hipMemsetAsync(cm, 0, NB * CM_N * sizeof(float), stream);
    cm_accum<<<numBlocks, 256, 0, stream>>>(input, target, partial, T);
    cm_reduce<<<NB * segs, 256, 0, stream>>>(partial, cm, blocksPerBatch, segs);
    cm_final<<<1, 512, 0, stream>>>(cm, out);
}